// Round 4
// baseline (149.019 us; speedup 1.0000x reference)
//
#include <hip/hip_runtime.h>
#include <hip/hip_fp16.h>

// Batched quantum-circuit sim. ONE kernel launch, 1-D grid, two block roles:
//  - blocks [0, 3*gx):      4q sims (A/B/C), one thread per element, role s
//    uniform per block (s = bx/gx). Scalar operand loads at point of use
//    (12 floats/role, compile-time indices) -- no r[56] bulk load.
//  - blocks [3*gx, 3*gx+gy): 7q sim, TWO lanes per element (qubit 0 = lane
//    parity), 64 amps/thread.
// amdgpu_waves_per_eu(4,4): pins regalloc at the 128-VGPR/4-wave step.
// R3 counters showed launch_bounds(256,4) let the allocator chase 8 waves ->
// VGPR=64 with the state spilled to scratch (WRITE_SIZE 33MB vs 4.7MB ideal).

#define DEVINL __device__ __forceinline__

typedef _Float16 hv2 __attribute__((ext_vector_type(2)));

struct C2 { __half2 rr, mp; };  // complex const (r,i): rr=(r,r), mp=(-i,+i)

DEVINL C2 mkc(float re, float im) {
  C2 c; c.rr = __floats2half2_rn(re, re); c.mp = __floats2half2_rn(-im, im); return c;
}
DEVINL __half2 mkamp(float re, float im) { return __floats2half2_rn(re, im); }
DEVINL __half2 swap2(__half2 v) { return __lowhigh2highlow(v); }
// (const u) * (amp v):  (r*vr - i*vi, r*vi + i*vr)
DEVINL __half2 cmulc(C2 u, __half2 v) { return __hfma2(u.rr, v, __hmul2(u.mp, swap2(v))); }

DEVINL float ampsq(__half2 v, float acc) {
#if __has_builtin(__builtin_amdgcn_fdot2)
  return __builtin_amdgcn_fdot2(__builtin_bit_cast(hv2, v), __builtin_bit_cast(hv2, v), acc, false);
#else
  float2 f = __half22float2(v);
  return fmaf(f.x, f.x, fmaf(f.y, f.y, acc));
#endif
}

constexpr int parc(int x) { x ^= x >> 4; x ^= x >> 2; x ^= x >> 1; return x & 1; }

struct c32 { float x, y; };
DEVINL c32 cmulf(c32 a, c32 b) { return { a.x*b.x - a.y*b.y, a.x*b.y + a.y*b.x }; }

// ---- lane^1 exchange via shfl_xor (battle-tested HIP path) -----------------
DEVINL __half2 lx1(__half2 v) {
  int q = __shfl_xor(__builtin_bit_cast(int, v), 1, 64);
  return __builtin_bit_cast(__half2, q);
}
DEVINL float lx1f(float v) { return __shfl_xor(v, 1, 64); }

// ---------------- generic gates (qubit W of N; mask = 1<<(N-1-W)) -----------

template<int N, int W>
DEVINL void g_ry(__half2* a, __half2 c2, __half2 s2, __half2 ns2) {
  constexpr int M = 1 << (N - 1 - W);
#pragma unroll
  for (int i = 0; i < (1 << N); ++i) if (!(i & M)) {
    const int j = i | M;
    __half2 v0 = a[i], v1 = a[j];
    a[i] = __hfma2(c2, v0, __hmul2(ns2, v1));
    a[j] = __hfma2(c2, v1, __hmul2(s2, v0));
  }
}

template<int N, int W>
DEVINL void g_u2(__half2* a, C2 u00, C2 u01, C2 u10, C2 u11) {
  constexpr int M = 1 << (N - 1 - W);
#pragma unroll
  for (int i = 0; i < (1 << N); ++i) if (!(i & M)) {
    const int j = i | M;
    __half2 v0 = a[i], v1 = a[j], v0s = swap2(v0), v1s = swap2(v1);
    a[i] = __hfma2(u00.rr, v0, __hfma2(u00.mp, v0s, __hfma2(u01.rr, v1, __hmul2(u01.mp, v1s))));
    a[j] = __hfma2(u10.rr, v0, __hfma2(u10.mp, v0s, __hfma2(u11.rr, v1, __hmul2(u11.mp, v1s))));
  }
}

template<int N, int C, int T>
DEVINL void g_cnot(__half2* a) {
  constexpr int CM = 1 << (N - 1 - C), TM = 1 << (N - 1 - T);
#pragma unroll
  for (int i = 0; i < (1 << N); ++i) if ((i & CM) && !(i & TM)) {
    const int j = i | TM;
    __half2 t = a[i]; a[i] = a[j]; a[j] = t;
  }
}

template<int N, int K>
DEVINL void chain_cnot(__half2* a) {
  if constexpr (K < N - 1) { g_cnot<N, K, K + 1>(a); chain_cnot<N, K + 1>(a); }
}

// ---------------- per-qubit coefficients (f32) ------------------------------
// forward: u = Rz(phi)Ry(pt)Rx(eta)|0>;  reverse merged: U = Rx(phi)Ry(pt)Rz(eta)

DEVINL void mk_u01(float ce, float se, float cp, float sp, float cf, float sf,
                   c32& u0, c32& u1) {
  u0 = cmulf({cf, -sf}, {cp * ce, sp * se});
  u1 = cmulf({cf,  sf}, {sp * ce, -cp * se});
}

DEVINL void mk_U(float ce, float se, float cp, float sp, float cf, float sf,
                 C2& U00, C2& U01, C2& U10, C2& U11) {
  c32 z = {ce, -se}, zb = {ce, se};
  c32 A = cmulf({cf * cp, -sf * sp}, z);
  c32 T = cmulf({cf * sp,  sf * cp}, zb);
  c32 Cc = cmulf({cf * sp, -sf * cp}, z);
  c32 D = cmulf({cf * cp,  sf * sp}, zb);
  U00 = mkc(A.x, A.y); U01 = mkc(-T.x, -T.y); U10 = mkc(Cc.x, Cc.y); U11 = mkc(D.x, D.y);
}

// per-qubit sincos loader (eta_i<0 -> eta=0)
DEVINL void load_sc(const float* __restrict__ xr, int eta_i, int pt_i, int phi_i,
                    float& ce, float& se, float& cp, float& sp, float& cf, float& sf) {
  float e = (eta_i < 0) ? 0.f : xr[eta_i];
  __sincosf(0.5f * e, &se, &ce);
  __sincosf(0.5f * xr[pt_i], &sp, &cp);
  __sincosf(0.5f * xr[phi_i], &sf, &cf);
}

// product state build by doubling (a[0] must be (1,0) on entry).
// step M's qubit lands at bit (N-1-M). CF(M,u0,u1) supplies the column.
template<int N, int M, class CF>
DEVINL void build_rec(__half2* a, CF cf) {
  if constexpr (M < N) {
    c32 u0, u1; cf(M, u0, u1);
    C2 c0 = mkc(u0.x, u0.y), c1 = mkc(u1.x, u1.y);
#pragma unroll
    for (int j = (1 << M) - 1; j >= 0; --j) {
      __half2 s = a[j];
      a[2 * j]     = cmulc(c0, s);
      a[2 * j + 1] = cmulc(c1, s);
    }
    build_rec<N, M + 1>(a, cf);
  }
}

template<int N, int K, class CF>
DEVINL void usweep_rec(__half2* a, CF cf) {
  if constexpr (K < N) {
    C2 U00, U01, U10, U11;
    cf(K, U00, U01, U10, U11);
    g_u2<N, K>(a, U00, U01, U10, U11);
    usweep_rec<N, K + 1>(a, cf);
  }
}

template<int N, int K, class CF>
DEVINL void ry_rec(__half2* a, CF cf) {
  if constexpr (K < N) {
    __half2 c2, s2, ns2;
    cf(K, c2, s2, ns2);
    g_ry<N, K>(a, c2, s2, ns2);
    ry_rec<N, K + 1>(a, cf);
  }
}

// ---------------- 4-qubit block I (verified math, scalar loads at use) ------

template<int I>
DEVINL void sim4h(const float* __restrict__ xr, const float* __restrict__ w, float* z) {
  constexpr int PT[3][4]  = {{5, 4, 35, 34}, {3, 33, 31, 2}, {28, 32, 15, 16}};
  constexpr int ETA[3][4] = {{9, 8, 45, 44}, {7, 43, 41, 6}, {38, 42, 19, 20}};
  constexpr int PHI[3][4] = {{13, 12, 55, 54}, {11, 53, 51, 10}, {48, 52, 23, 24}};
  __half2 a[16];
  a[0] = mkamp(1.f, 0.f);
  build_rec<4, 0>(a, [&](int M, c32& u0, c32& u1) {
    float ce, se, cp, sp, cf, sf;
    load_sc(xr, ETA[I][M], PT[I][M], PHI[I][M], ce, se, cp, sp, cf, sf);
    mk_u01(ce, se, cp, sp, cf, sf, u0, u1);
  });
  chain_cnot<4, 0>(a);
  usweep_rec<4, 0>(a, [&](int K, C2& U00, C2& U01, C2& U10, C2& U11) {
    float ce, se, cp, sp, cf, sf;
    load_sc(xr, ETA[I][K], PT[I][K], PHI[I][K], ce, se, cp, sp, cf, sf);
    mk_U(ce, se, cp, sp, cf, sf, U00, U01, U10, U11);
  });

  // t->l CNOT block == flip q0,q1 (mask 12) iff parity(b2,b3) (i&3)
#pragma unroll
  for (int i = 0; i < 16; ++i)
    if (parc(i & 3) && !(i & 8)) { __half2 t = a[i]; a[i] = a[i ^ 12]; a[i ^ 12] = t; }

  ry_rec<4, 0>(a, [&](int K, __half2& c2, __half2& s2, __half2& ns2) {
    float sv, cv; __sincosf(0.5f * w[K], &sv, &cv);
    c2 = __floats2half2_rn(cv, cv);
    s2 = __floats2half2_rn(sv, sv);
    ns2 = __floats2half2_rn(-sv, -sv);
  });

  // l->t CNOT block == flip q2,q3 (mask 3) iff parity(b0,b1) (i&12)
#pragma unroll
  for (int i = 0; i < 16; ++i)
    if (parc(i & 12) && !(i & 2)) { __half2 t = a[i]; a[i] = a[i ^ 3]; a[i ^ 3] = t; }

  float cls[4];
#pragma unroll
  for (int c = 0; c < 4; ++c) cls[c] = 0.f;
#pragma unroll
  for (int i = 0; i < 16; ++i) cls[i & 3] = ampsq(a[i], cls[i & 3]);
  float z0 = 0.f, z1 = 0.f;
#pragma unroll
  for (int c = 0; c < 4; ++c) {
    z0 += (c & 2) ? -cls[c] : cls[c];
    z1 += (c & 1) ? -cls[c] : cls[c];
  }
  z[0] = z0; z[1] = z1;
}

// ---------------- role bodies ----------------------------------------------

DEVINL void role4(const float* __restrict__ x,
                  const float* __restrict__ wA, const float* __restrict__ wB,
                  const float* __restrict__ wC,
                  float* __restrict__ out, int B, int s, int rb) {
  const int b = rb * 256 + threadIdx.x;
  if (b >= B) return;
  const float* xr = x + (size_t)b * 56;

  float o[2];
  if (s == 0)      sim4h<0>(xr, wA, o);
  else if (s == 1) sim4h<1>(xr, wB, o);
  else             sim4h<2>(xr, wC, o);

  float* op = out + (size_t)b * 9 + 2 * s;
  op[0] = o[0]; op[1] = o[1];
}

// 7q: qubit 0 = lane parity; local index i = qubits 1..6, qubit k at bit 6-k.
DEVINL void role7(const float* __restrict__ x, const float* __restrict__ wD,
                  float* __restrict__ out, int B, int rb) {
  const int t = rb * 256 + threadIdx.x;
  const int b = t >> 1;
  if (b >= B) return;                 // pairs both-valid or both-invalid
  const bool po = (t & 1) != 0;       // this lane's value of qubit 0

  constexpr int PT[7]  = {0, 14, 30, 26, 29, 27, 17};
  constexpr int ETA[7] = {-1, 18, 40, 36, 39, 37, 21};  // -1 -> zeros (None)
  constexpr int PHI[7] = {1, 22, 50, 46, 49, 47, 25};

  const float* xr = x + (size_t)b * 56;

  __half2 a[64];
  a[0] = mkamp(1.f, 0.f);
  // build qubits 1..6 locally: step M = qubit M+1 -> local bit 5-M = 6-(M+1)
  build_rec<6, 0>(a, [&](int M, c32& u0, c32& u1) {
    const int k = M + 1;
    float ce, se, cp, sp, cf, sf;
    load_sc(xr, ETA[k], PT[k], PHI[k], ce, se, cp, sp, cf, sf);
    mk_u01(ce, se, cp, sp, cf, sf, u0, u1);
  });
  { // qubit-0 product factor, selected by lane parity
    float ce, se, cp, sp, cf, sf;
    load_sc(xr, ETA[0], PT[0], PHI[0], ce, se, cp, sp, cf, sf);
    c32 u0, u1; mk_u01(ce, se, cp, sp, cf, sf, u0, u1);
    C2 c0 = mkc(po ? u1.x : u0.x, po ? u1.y : u0.y);
#pragma unroll
    for (int i = 0; i < 64; ++i) a[i] = cmulc(c0, a[i]);
  }

  // CNOT(0,1): lanes with q0=1 flip local bit5 (pure per-lane swap)
#pragma unroll
  for (int i = 0; i < 32; ++i) {
    const int j = i | 32;
    __half2 t0 = po ? a[j] : a[i];
    __half2 t1 = po ? a[i] : a[j];
    a[i] = t0; a[j] = t1;
  }
  // CNOT(1,2)..(5,6): local chain; g_cnot<6,C,C+1> = qubits (C+1, C+2)
  chain_cnot<6, 0>(a);

  // merged-U sweep: qubit 0 (cross-lane), then qubits 1..6 (local)
  {
    float ce, se, cp, sp, cf, sf;
    load_sc(xr, ETA[0], PT[0], PHI[0], ce, se, cp, sp, cf, sf);
    C2 U00, U01, U10, U11;
    mk_U(ce, se, cp, sp, cf, sf, U00, U01, U10, U11);
    // out_lane = UA*mine + UB*partner;  UA = po?U11:U00, UB = po?U10:U01
    C2 UA, UB;
    UA.rr = po ? U11.rr : U00.rr; UA.mp = po ? U11.mp : U00.mp;
    UB.rr = po ? U10.rr : U01.rr; UB.mp = po ? U10.mp : U01.mp;
#pragma unroll
    for (int i = 0; i < 64; ++i) {
      __half2 m = a[i], q = lx1(m);
      a[i] = __hfma2(UA.rr, m, __hfma2(UA.mp, swap2(m),
             __hfma2(UB.rr, q, __hmul2(UB.mp, swap2(q)))));
    }
  }
  usweep_rec<6, 0>(a, [&](int W, C2& U00, C2& U01, C2& U10, C2& U11) {
    const int k = W + 1;   // g_u2<6,W> mask 1<<(5-W) == qubit k local bit 6-k
    float ce, se, cp, sp, cf, sf;
    load_sc(xr, ETA[k], PT[k], PHI[k], ce, se, cp, sp, cf, sf);
    mk_U(ce, se, cp, sp, cf, sf, U00, U01, U10, U11);
  });

  // depth loop kept rolled: body stays in L1I
#pragma unroll 1
  for (int d = 0; d < 4; ++d) {
    // P1 (t->l): flip q0..q3 iff parity(q4,q5,q6).  Pairs {i, i^0x38} across
    // lanes: a[i]_po <- old a[i^0x38]_{1-po}
#pragma unroll
    for (int i = 0; i < 64; ++i)
      if (parc(i & 7) && !(i & 0x20)) {
        const int j = i ^ 0x38;
        __half2 t0 = lx1(a[j]);
        __half2 t1 = lx1(a[i]);
        a[i] = t0; a[j] = t1;
      }

    // Ry qubit 0 (cross-lane): out = c*mine + (po? s : -s)*partner
    {
      float sv, cv; __sincosf(0.5f * wD[7 * d], &sv, &cv);
      __half2 c2v = __floats2half2_rn(cv, cv);
      __half2 sp2 = __floats2half2_rn(po ? sv : -sv, po ? sv : -sv);
#pragma unroll
      for (int i = 0; i < 64; ++i) {
        __half2 q = lx1(a[i]);
        a[i] = __hfma2(c2v, a[i], __hmul2(sp2, q));
      }
    }
    // Ry qubits 1..6 (local)
    ry_rec<6, 0>(a, [&](int W, __half2& c2, __half2& s2, __half2& ns2) {
      float sv, cv; __sincosf(0.5f * wD[7 * d + W + 1], &sv, &cv);
      c2 = __floats2half2_rn(cv, cv);
      s2 = __floats2half2_rn(sv, sv);
      ns2 = __floats2half2_rn(-sv, -sv);
    });

    // P2 (l->t): flip q4..q6 (local ^7) iff parity(q0..q3) = po ^ parc(i&0x38)
#pragma unroll
    for (int i = 0; i < 64; ++i)
      if (!(i & 4)) {            // rep of pair {i, i^7}
        const int j = i ^ 7;
        __half2 t0, t1;
        if (parc(i & 0x38)) { t0 = po ? a[i] : a[j]; t1 = po ? a[j] : a[i]; }
        else                { t0 = po ? a[j] : a[i]; t1 = po ? a[i] : a[j]; }
        a[i] = t0; a[j] = t1;
      }
  }

  // readout: class c = q4q5q6 = i&7 (local); pair-sum cross-lane
  float cls[8];
#pragma unroll
  for (int c = 0; c < 8; ++c) cls[c] = 0.f;
#pragma unroll
  for (int i = 0; i < 64; ++i) cls[i & 7] = ampsq(a[i], cls[i & 7]);
  float z4 = 0.f, z5 = 0.f, z6 = 0.f;
#pragma unroll
  for (int c = 0; c < 8; ++c) {
    z4 += (c & 4) ? -cls[c] : cls[c];
    z5 += (c & 2) ? -cls[c] : cls[c];
    z6 += (c & 1) ? -cls[c] : cls[c];
  }
  z4 += lx1f(z4); z5 += lx1f(z5); z6 += lx1f(z6);
  if (!po) {
    float* op = out + (size_t)b * 9 + 6;
    op[0] = z4; op[1] = z5; op[2] = z6;
  }
}

// ---------------- single fused-dispatch kernel ------------------------------

__global__ void
__attribute__((amdgpu_flat_work_group_size(256, 256), amdgpu_waves_per_eu(4, 4)))
k_all(const float* __restrict__ x,
      const float* __restrict__ wA, const float* __restrict__ wB,
      const float* __restrict__ wC, const float* __restrict__ wD,
      float* __restrict__ out, int B, int gx) {
  const int bx = blockIdx.x;
  if (bx < 3 * gx) {
    const int s = (bx >= 2 * gx) ? 2 : (int)(bx >= gx);  // block-uniform
    role4(x, wA, wB, wC, out, B, s, bx - s * gx);
  } else {
    role7(x, wD, out, B, bx - 3 * gx);
  }
}

// ---------------- launch ----------------------------------------------------

extern "C" void kernel_launch(void* const* d_in, const int* in_sizes, int n_in,
                              void* d_out, int out_size, void* d_ws, size_t ws_size,
                              hipStream_t stream) {
  const float* x  = (const float*)d_in[0];
  const float* wA = (const float*)d_in[1];
  const float* wB = (const float*)d_in[2];
  const float* wC = (const float*)d_in[3];
  const float* wD = (const float*)d_in[4];
  float* out = (float*)d_out;
  const int B = in_sizes[0] / 56;
  const int threads = 256;

  const int gx = (B + threads - 1) / threads;          // blocks per 4q role
  const int gy = (2 * B + threads - 1) / threads;      // blocks for 7q role
  k_all<<<3 * gx + gy, threads, 0, stream>>>(x, wA, wB, wC, wD, out, B, gx);
}

// Round 5
// 143.067 us; speedup vs baseline: 1.0416x; 1.0416x over previous
//
#include <hip/hip_runtime.h>
#include <hip/hip_fp16.h>

// Batched quantum-circuit sim. ONE kernel launch, 1-D grid, two block roles:
//  - blocks [0, 3*gx):       4q sims (A/B/C), one thread per element.
//  - blocks [3*gx, 3*gx+gy): 7q sim, FOUR lanes per element (qubits 0,1 =
//    lane bits), 32 amps/thread -> live set ~55 VGPR, fits the 64-VGPR/8-wave
//    allocation the compiler insists on (R3/R4: a[64] at VGPR=64 forced ~25MB
//    of spill round-trips; 4-lane split removes the pressure entirely).
// Cross-lane ops via __shfl_xor 1/2/3 (verified path from R3).

#define DEVINL __device__ __forceinline__

typedef _Float16 hv2 __attribute__((ext_vector_type(2)));

struct C2 { __half2 rr, mp; };  // complex const (r,i): rr=(r,r), mp=(-i,+i)

DEVINL C2 mkc(float re, float im) {
  C2 c; c.rr = __floats2half2_rn(re, re); c.mp = __floats2half2_rn(-im, im); return c;
}
DEVINL __half2 mkamp(float re, float im) { return __floats2half2_rn(re, im); }
DEVINL __half2 swap2(__half2 v) { return __lowhigh2highlow(v); }
// (const u) * (amp v):  (r*vr - i*vi, r*vi + i*vr)
DEVINL __half2 cmulc(C2 u, __half2 v) { return __hfma2(u.rr, v, __hmul2(u.mp, swap2(v))); }

DEVINL float ampsq(__half2 v, float acc) {
#if __has_builtin(__builtin_amdgcn_fdot2)
  return __builtin_amdgcn_fdot2(__builtin_bit_cast(hv2, v), __builtin_bit_cast(hv2, v), acc, false);
#else
  float2 f = __half22float2(v);
  return fmaf(f.x, f.x, fmaf(f.y, f.y, acc));
#endif
}

constexpr int parc(int x) { x ^= x >> 4; x ^= x >> 2; x ^= x >> 1; return x & 1; }

struct c32 { float x, y; };
DEVINL c32 cmulf(c32 a, c32 b) { return { a.x*b.x - a.y*b.y, a.x*b.y + a.y*b.x }; }

// ---- lane^k exchange via shfl_xor (battle-tested HIP path) -----------------
template<int K>
DEVINL __half2 lxk(__half2 v) {
  int q = __shfl_xor(__builtin_bit_cast(int, v), K, 64);
  return __builtin_bit_cast(__half2, q);
}
template<int K>
DEVINL float lxkf(float v) { return __shfl_xor(v, K, 64); }

// ---------------- generic gates (qubit W of N; mask = 1<<(N-1-W)) -----------

template<int N, int W>
DEVINL void g_ry(__half2* a, __half2 c2, __half2 s2, __half2 ns2) {
  constexpr int M = 1 << (N - 1 - W);
#pragma unroll
  for (int i = 0; i < (1 << N); ++i) if (!(i & M)) {
    const int j = i | M;
    __half2 v0 = a[i], v1 = a[j];
    a[i] = __hfma2(c2, v0, __hmul2(ns2, v1));
    a[j] = __hfma2(c2, v1, __hmul2(s2, v0));
  }
}

template<int N, int W>
DEVINL void g_u2(__half2* a, C2 u00, C2 u01, C2 u10, C2 u11) {
  constexpr int M = 1 << (N - 1 - W);
#pragma unroll
  for (int i = 0; i < (1 << N); ++i) if (!(i & M)) {
    const int j = i | M;
    __half2 v0 = a[i], v1 = a[j], v0s = swap2(v0), v1s = swap2(v1);
    a[i] = __hfma2(u00.rr, v0, __hfma2(u00.mp, v0s, __hfma2(u01.rr, v1, __hmul2(u01.mp, v1s))));
    a[j] = __hfma2(u10.rr, v0, __hfma2(u10.mp, v0s, __hfma2(u11.rr, v1, __hmul2(u11.mp, v1s))));
  }
}

template<int N, int C, int T>
DEVINL void g_cnot(__half2* a) {
  constexpr int CM = 1 << (N - 1 - C), TM = 1 << (N - 1 - T);
#pragma unroll
  for (int i = 0; i < (1 << N); ++i) if ((i & CM) && !(i & TM)) {
    const int j = i | TM;
    __half2 t = a[i]; a[i] = a[j]; a[j] = t;
  }
}

template<int N, int K>
DEVINL void chain_cnot(__half2* a) {
  if constexpr (K < N - 1) { g_cnot<N, K, K + 1>(a); chain_cnot<N, K + 1>(a); }
}

// ---------------- per-qubit coefficients (f32) ------------------------------
// forward: u = Rz(phi)Ry(pt)Rx(eta)|0>;  reverse merged: U = Rx(phi)Ry(pt)Rz(eta)

DEVINL void mk_u01(float ce, float se, float cp, float sp, float cf, float sf,
                   c32& u0, c32& u1) {
  u0 = cmulf({cf, -sf}, {cp * ce, sp * se});
  u1 = cmulf({cf,  sf}, {sp * ce, -cp * se});
}

DEVINL void mk_U(float ce, float se, float cp, float sp, float cf, float sf,
                 C2& U00, C2& U01, C2& U10, C2& U11) {
  c32 z = {ce, -se}, zb = {ce, se};
  c32 A = cmulf({cf * cp, -sf * sp}, z);
  c32 T = cmulf({cf * sp,  sf * cp}, zb);
  c32 Cc = cmulf({cf * sp, -sf * cp}, z);
  c32 D = cmulf({cf * cp,  sf * sp}, zb);
  U00 = mkc(A.x, A.y); U01 = mkc(-T.x, -T.y); U10 = mkc(Cc.x, Cc.y); U11 = mkc(D.x, D.y);
}

// per-qubit sincos loader (eta_i<0 -> eta=0)
DEVINL void load_sc(const float* __restrict__ xr, int eta_i, int pt_i, int phi_i,
                    float& ce, float& se, float& cp, float& sp, float& cf, float& sf) {
  float e = (eta_i < 0) ? 0.f : xr[eta_i];
  __sincosf(0.5f * e, &se, &ce);
  __sincosf(0.5f * xr[pt_i], &sp, &cp);
  __sincosf(0.5f * xr[phi_i], &sf, &cf);
}

// product state build by doubling (a[0] must be (1,0) on entry).
// step M's qubit lands at bit (N-1-M). CF(M,u0,u1) supplies the column.
template<int N, int M, class CF>
DEVINL void build_rec(__half2* a, CF cf) {
  if constexpr (M < N) {
    c32 u0, u1; cf(M, u0, u1);
    C2 c0 = mkc(u0.x, u0.y), c1 = mkc(u1.x, u1.y);
#pragma unroll
    for (int j = (1 << M) - 1; j >= 0; --j) {
      __half2 s = a[j];
      a[2 * j]     = cmulc(c0, s);
      a[2 * j + 1] = cmulc(c1, s);
    }
    build_rec<N, M + 1>(a, cf);
  }
}

template<int N, int K, class CF>
DEVINL void usweep_rec(__half2* a, CF cf) {
  if constexpr (K < N) {
    C2 U00, U01, U10, U11;
    cf(K, U00, U01, U10, U11);
    g_u2<N, K>(a, U00, U01, U10, U11);
    usweep_rec<N, K + 1>(a, cf);
  }
}

template<int N, int K, class CF>
DEVINL void ry_rec(__half2* a, CF cf) {
  if constexpr (K < N) {
    __half2 c2, s2, ns2;
    cf(K, c2, s2, ns2);
    g_ry<N, K>(a, c2, s2, ns2);
    ry_rec<N, K + 1>(a, cf);
  }
}

// ---------------- 4-qubit block I (verified math, scalar loads at use) ------

template<int I>
DEVINL void sim4h(const float* __restrict__ xr, const float* __restrict__ w, float* z) {
  constexpr int PT[3][4]  = {{5, 4, 35, 34}, {3, 33, 31, 2}, {28, 32, 15, 16}};
  constexpr int ETA[3][4] = {{9, 8, 45, 44}, {7, 43, 41, 6}, {38, 42, 19, 20}};
  constexpr int PHI[3][4] = {{13, 12, 55, 54}, {11, 53, 51, 10}, {48, 52, 23, 24}};
  __half2 a[16];
  a[0] = mkamp(1.f, 0.f);
  build_rec<4, 0>(a, [&](int M, c32& u0, c32& u1) {
    float ce, se, cp, sp, cf, sf;
    load_sc(xr, ETA[I][M], PT[I][M], PHI[I][M], ce, se, cp, sp, cf, sf);
    mk_u01(ce, se, cp, sp, cf, sf, u0, u1);
  });
  chain_cnot<4, 0>(a);
  usweep_rec<4, 0>(a, [&](int K, C2& U00, C2& U01, C2& U10, C2& U11) {
    float ce, se, cp, sp, cf, sf;
    load_sc(xr, ETA[I][K], PT[I][K], PHI[I][K], ce, se, cp, sp, cf, sf);
    mk_U(ce, se, cp, sp, cf, sf, U00, U01, U10, U11);
  });

  // t->l CNOT block == flip q0,q1 (mask 12) iff parity(b2,b3) (i&3)
#pragma unroll
  for (int i = 0; i < 16; ++i)
    if (parc(i & 3) && !(i & 8)) { __half2 t = a[i]; a[i] = a[i ^ 12]; a[i ^ 12] = t; }

  ry_rec<4, 0>(a, [&](int K, __half2& c2, __half2& s2, __half2& ns2) {
    float sv, cv; __sincosf(0.5f * w[K], &sv, &cv);
    c2 = __floats2half2_rn(cv, cv);
    s2 = __floats2half2_rn(sv, sv);
    ns2 = __floats2half2_rn(-sv, -sv);
  });

  // l->t CNOT block == flip q2,q3 (mask 3) iff parity(b0,b1) (i&12)
#pragma unroll
  for (int i = 0; i < 16; ++i)
    if (parc(i & 12) && !(i & 2)) { __half2 t = a[i]; a[i] = a[i ^ 3]; a[i ^ 3] = t; }

  float cls[4];
#pragma unroll
  for (int c = 0; c < 4; ++c) cls[c] = 0.f;
#pragma unroll
  for (int i = 0; i < 16; ++i) cls[i & 3] = ampsq(a[i], cls[i & 3]);
  float z0 = 0.f, z1 = 0.f;
#pragma unroll
  for (int c = 0; c < 4; ++c) {
    z0 += (c & 2) ? -cls[c] : cls[c];
    z1 += (c & 1) ? -cls[c] : cls[c];
  }
  z[0] = z0; z[1] = z1;
}

// ---------------- role bodies ----------------------------------------------

DEVINL void role4(const float* __restrict__ x,
                  const float* __restrict__ wA, const float* __restrict__ wB,
                  const float* __restrict__ wC,
                  float* __restrict__ out, int B, int s, int rb) {
  const int b = rb * 256 + threadIdx.x;
  if (b >= B) return;
  const float* xr = x + (size_t)b * 56;

  float o[2];
  if (s == 0)      sim4h<0>(xr, wA, o);
  else if (s == 1) sim4h<1>(xr, wB, o);
  else             sim4h<2>(xr, wC, o);

  float* op = out + (size_t)b * 9 + 2 * s;
  op[0] = o[0]; op[1] = o[1];
}

// 7q, 4 lanes/element: sub = t&3 = (q0<<1)|q1. Local index i (5 bits):
// qubit k>=2 at bit 6-k (q2=16, q3=8, q4=4, q5=2, q6=1).
// q0 partner = lane^2, q1 partner = lane^1.
DEVINL void role7(const float* __restrict__ x, const float* __restrict__ wD,
                  float* __restrict__ out, int B, int rb) {
  const int t = rb * 256 + threadIdx.x;
  const int b = t >> 2;
  if (b >= B) return;                 // quads all-valid or all-invalid
  const int sub = t & 3;
  const bool b0 = (sub & 2) != 0;     // qubit 0 value
  const bool b1 = (sub & 1) != 0;     // qubit 1 value

  constexpr int PT[7]  = {0, 14, 30, 26, 29, 27, 17};
  constexpr int ETA[7] = {-1, 18, 40, 36, 39, 37, 21};  // -1 -> zeros (None)
  constexpr int PHI[7] = {1, 22, 50, 46, 49, 47, 25};

  const float* xr = x + (size_t)b * 56;

  __half2 a[32];
  a[0] = mkamp(1.f, 0.f);
  // build qubits 2..6 locally: step M = qubit M+2 -> local bit 4-M = 6-(M+2)
  build_rec<5, 0>(a, [&](int M, c32& u0, c32& u1) {
    const int k = M + 2;
    float ce, se, cp, sp, cf, sf;
    load_sc(xr, ETA[k], PT[k], PHI[k], ce, se, cp, sp, cf, sf);
    mk_u01(ce, se, cp, sp, cf, sf, u0, u1);
  });
  { // combined q0,q1 product factor selected by lane bits
    float ce, se, cp, sp, cf, sf;
    load_sc(xr, ETA[0], PT[0], PHI[0], ce, se, cp, sp, cf, sf);
    c32 q0u0, q0u1; mk_u01(ce, se, cp, sp, cf, sf, q0u0, q0u1);
    load_sc(xr, ETA[1], PT[1], PHI[1], ce, se, cp, sp, cf, sf);
    c32 q1u0, q1u1; mk_u01(ce, se, cp, sp, cf, sf, q1u0, q1u1);
    c32 f0 = b0 ? q0u1 : q0u0;
    c32 f1 = b1 ? q1u1 : q1u0;
    c32 f = cmulf(f0, f1);
    C2 cf2 = mkc(f.x, f.y);
#pragma unroll
    for (int i = 0; i < 32; ++i) a[i] = cmulc(cf2, a[i]);
  }

  // CNOT(0,1): lanes with q0=1 exchange with partner over q1 (lane^1)
#pragma unroll
  for (int i = 0; i < 32; ++i) {
    __half2 q = lxk<1>(a[i]);
    a[i] = b0 ? q : a[i];
  }
  // CNOT(1,2): lanes with q1=1 flip local bit4 (q2)
#pragma unroll
  for (int i = 0; i < 16; ++i) {
    const int j = i | 16;
    __half2 lo = a[i], hi = a[j];
    a[i] = b1 ? hi : lo;
    a[j] = b1 ? lo : hi;
  }
  // CNOT(2,3)..(5,6): local chain (renames)
  chain_cnot<5, 0>(a);

  // merged-U sweep: q0 (lane^2), q1 (lane^1), then q2..q6 local
  {
    float ce, se, cp, sp, cf, sf;
    load_sc(xr, ETA[0], PT[0], PHI[0], ce, se, cp, sp, cf, sf);
    C2 U00, U01, U10, U11;
    mk_U(ce, se, cp, sp, cf, sf, U00, U01, U10, U11);
    C2 UA, UB;  // out = UA*mine + UB*partner
    UA.rr = b0 ? U11.rr : U00.rr; UA.mp = b0 ? U11.mp : U00.mp;
    UB.rr = b0 ? U10.rr : U01.rr; UB.mp = b0 ? U10.mp : U01.mp;
#pragma unroll
    for (int i = 0; i < 32; ++i) {
      __half2 m = a[i], q = lxk<2>(m);
      a[i] = __hfma2(UA.rr, m, __hfma2(UA.mp, swap2(m),
             __hfma2(UB.rr, q, __hmul2(UB.mp, swap2(q)))));
    }
  }
  {
    float ce, se, cp, sp, cf, sf;
    load_sc(xr, ETA[1], PT[1], PHI[1], ce, se, cp, sp, cf, sf);
    C2 U00, U01, U10, U11;
    mk_U(ce, se, cp, sp, cf, sf, U00, U01, U10, U11);
    C2 UA, UB;
    UA.rr = b1 ? U11.rr : U00.rr; UA.mp = b1 ? U11.mp : U00.mp;
    UB.rr = b1 ? U10.rr : U01.rr; UB.mp = b1 ? U10.mp : U01.mp;
#pragma unroll
    for (int i = 0; i < 32; ++i) {
      __half2 m = a[i], q = lxk<1>(m);
      a[i] = __hfma2(UA.rr, m, __hfma2(UA.mp, swap2(m),
             __hfma2(UB.rr, q, __hmul2(UB.mp, swap2(q)))));
    }
  }
  usweep_rec<5, 0>(a, [&](int W, C2& U00, C2& U01, C2& U10, C2& U11) {
    const int k = W + 2;
    float ce, se, cp, sp, cf, sf;
    load_sc(xr, ETA[k], PT[k], PHI[k], ce, se, cp, sp, cf, sf);
    mk_U(ce, se, cp, sp, cf, sf, U00, U01, U10, U11);
  });

  // depth loop kept rolled: body stays in L1I
#pragma unroll 1
  for (int d = 0; d < 4; ++d) {
    // P1 (t->l): flip q0..q3 iff parity(q4,q5,q6)=parc(i&7).
    // Pairs {(lane,i),(lane^3,i^0x18)}: a[i] <- old partner a[i^0x18]
#pragma unroll
    for (int i = 0; i < 32; ++i)
      if (parc(i & 7) && !(i & 0x10)) {
        const int j = i ^ 0x18;
        __half2 t0 = lxk<3>(a[j]);
        __half2 t1 = lxk<3>(a[i]);
        a[i] = t0; a[j] = t1;
      }

    // Ry q0 (lane^2): out = c*mine + (b0? s : -s)*partner
    {
      float sv, cv; __sincosf(0.5f * wD[7 * d], &sv, &cv);
      __half2 c2v = __floats2half2_rn(cv, cv);
      __half2 se2 = __floats2half2_rn(b0 ? sv : -sv, b0 ? sv : -sv);
#pragma unroll
      for (int i = 0; i < 32; ++i) {
        __half2 q = lxk<2>(a[i]);
        a[i] = __hfma2(c2v, a[i], __hmul2(se2, q));
      }
    }
    // Ry q1 (lane^1)
    {
      float sv, cv; __sincosf(0.5f * wD[7 * d + 1], &sv, &cv);
      __half2 c2v = __floats2half2_rn(cv, cv);
      __half2 se2 = __floats2half2_rn(b1 ? sv : -sv, b1 ? sv : -sv);
#pragma unroll
      for (int i = 0; i < 32; ++i) {
        __half2 q = lxk<1>(a[i]);
        a[i] = __hfma2(c2v, a[i], __hmul2(se2, q));
      }
    }
    // Ry q2..q6 local
    ry_rec<5, 0>(a, [&](int W, __half2& c2, __half2& s2, __half2& ns2) {
      float sv, cv; __sincosf(0.5f * wD[7 * d + W + 2], &sv, &cv);
      c2 = __floats2half2_rn(cv, cv);
      s2 = __floats2half2_rn(sv, sv);
      ns2 = __floats2half2_rn(-sv, -sv);
    });

    // P2 (l->t): flip q4..q6 (local ^7) iff parity(q0..q3) =
    // parc(sub) ^ parc(i&0x18)  (lane-local swap)
    {
      const bool ps = b0 ^ b1;
#pragma unroll
      for (int i = 0; i < 32; ++i)
        if (!(i & 4)) {          // rep of pair {i, i^7}
          const int j = i ^ 7;
          const bool cond = parc(i & 0x18) ? !ps : ps;
          __half2 lo = a[i], hi = a[j];
          a[i] = cond ? hi : lo;
          a[j] = cond ? lo : hi;
        }
    }
  }

  // readout: class c = q4q5q6 = i&7 (local); quad-sum cross-lane
  float cls[8];
#pragma unroll
  for (int c = 0; c < 8; ++c) cls[c] = 0.f;
#pragma unroll
  for (int i = 0; i < 32; ++i) cls[i & 7] = ampsq(a[i], cls[i & 7]);
  float z4 = 0.f, z5 = 0.f, z6 = 0.f;
#pragma unroll
  for (int c = 0; c < 8; ++c) {
    z4 += (c & 4) ? -cls[c] : cls[c];
    z5 += (c & 2) ? -cls[c] : cls[c];
    z6 += (c & 1) ? -cls[c] : cls[c];
  }
  z4 += lxkf<1>(z4); z5 += lxkf<1>(z5); z6 += lxkf<1>(z6);
  z4 += lxkf<2>(z4); z5 += lxkf<2>(z5); z6 += lxkf<2>(z6);
  if (sub == 0) {
    float* op = out + (size_t)b * 9 + 6;
    op[0] = z4; op[1] = z5; op[2] = z6;
  }
}

// ---------------- single fused-dispatch kernel ------------------------------

__global__ void __launch_bounds__(256, 4)
k_all(const float* __restrict__ x,
      const float* __restrict__ wA, const float* __restrict__ wB,
      const float* __restrict__ wC, const float* __restrict__ wD,
      float* __restrict__ out, int B, int gx) {
  const int bx = blockIdx.x;
  if (bx < 3 * gx) {
    const int s = (bx >= 2 * gx) ? 2 : (int)(bx >= gx);  // block-uniform
    role4(x, wA, wB, wC, out, B, s, bx - s * gx);
  } else {
    role7(x, wD, out, B, bx - 3 * gx);
  }
}

// ---------------- launch ----------------------------------------------------

extern "C" void kernel_launch(void* const* d_in, const int* in_sizes, int n_in,
                              void* d_out, int out_size, void* d_ws, size_t ws_size,
                              hipStream_t stream) {
  const float* x  = (const float*)d_in[0];
  const float* wA = (const float*)d_in[1];
  const float* wB = (const float*)d_in[2];
  const float* wC = (const float*)d_in[3];
  const float* wD = (const float*)d_in[4];
  float* out = (float*)d_out;
  const int B = in_sizes[0] / 56;
  const int threads = 256;

  const int gx = (B + threads - 1) / threads;          // blocks per 4q role
  const int gy = (4 * B + threads - 1) / threads;      // blocks for 7q role
  k_all<<<3 * gx + gy, threads, 0, stream>>>(x, wA, wB, wC, wD, out, B, gx);
}

// Round 6
// 140.048 us; speedup vs baseline: 1.0641x; 1.0216x over previous
//
#include <hip/hip_runtime.h>
#include <hip/hip_fp16.h>

// Batched quantum-circuit sim. ONE kernel launch, 1-D grid, two block roles:
//  - blocks [0, 3*gx):       4q sims (A/B/C), one thread per element.
//  - blocks [3*gx, 3*gx+gy): 7q sim, TWO lanes per element (qubit 0 = lane
//    parity), 64 amps/thread.
// KEY CHANGE (R6): state held in ext_vector_type SSA vectors (u32x64/u32x16),
// not __half2 arrays. R3-R5 all reported VGPR_Count=64 with huge scratch
// traffic -> SROA never promoted the arrays; every gate sweep round-tripped
// the state through scratch (the real ~100-150us limiter). Vectors with
// constant-index extract/insert cannot be demoted to memory by SROA.
// waves_per_eu(2,4): allocator may use up to 256 VGPR, won't chase 8 waves.

#define DEVINL __device__ __forceinline__

typedef _Float16 hv2 __attribute__((ext_vector_type(2)));
typedef unsigned int u32;
typedef u32 vreg16 __attribute__((ext_vector_type(16)));
typedef u32 vreg64 __attribute__((ext_vector_type(64)));

struct C2 { __half2 rr, mp; };  // complex const (r,i): rr=(r,r), mp=(-i,+i)

DEVINL C2 mkc(float re, float im) {
  C2 c; c.rr = __floats2half2_rn(re, re); c.mp = __floats2half2_rn(-im, im); return c;
}
DEVINL __half2 mkamp(float re, float im) { return __floats2half2_rn(re, im); }
DEVINL __half2 swap2(__half2 v) { return __lowhigh2highlow(v); }
// (const u) * (amp v):  (r*vr - i*vi, r*vi + i*vr)
DEVINL __half2 cmulc(C2 u, __half2 v) { return __hfma2(u.rr, v, __hmul2(u.mp, swap2(v))); }

DEVINL float ampsq(__half2 v, float acc) {
#if __has_builtin(__builtin_amdgcn_fdot2)
  return __builtin_amdgcn_fdot2(__builtin_bit_cast(hv2, v), __builtin_bit_cast(hv2, v), acc, false);
#else
  float2 f = __half22float2(v);
  return fmaf(f.x, f.x, fmaf(f.y, f.y, acc));
#endif
}

constexpr int parc(int x) { x ^= x >> 4; x ^= x >> 2; x ^= x >> 1; return x & 1; }

struct c32 { float x, y; };
DEVINL c32 cmulf(c32 a, c32 b) { return { a.x*b.x - a.y*b.y, a.x*b.y + a.y*b.x }; }

// ---- SSA state accessors (constant-index extract/insert) -------------------
template<class VT>
DEVINL __half2 vget(const VT& A, int i) { return __builtin_bit_cast(__half2, (u32)A[i]); }
template<class VT>
DEVINL void vset(VT& A, int i, __half2 v) { A[i] = __builtin_bit_cast(u32, v); }

// ---- lane^1 exchange via shfl_xor (verified path from R3) ------------------
DEVINL __half2 lx1(__half2 v) {
  int q = __shfl_xor(__builtin_bit_cast(int, v), 1, 64);
  return __builtin_bit_cast(__half2, q);
}
DEVINL float lx1f(float v) { return __shfl_xor(v, 1, 64); }

// ---------------- generic gates (qubit W of N; mask = 1<<(N-1-W)) -----------

template<int N, int W, class VT>
DEVINL void g_ry(VT& A, __half2 c2, __half2 s2, __half2 ns2) {
  constexpr int M = 1 << (N - 1 - W);
#pragma unroll
  for (int i = 0; i < (1 << N); ++i) if (!(i & M)) {
    const int j = i | M;
    __half2 v0 = vget(A, i), v1 = vget(A, j);
    vset(A, i, __hfma2(c2, v0, __hmul2(ns2, v1)));
    vset(A, j, __hfma2(c2, v1, __hmul2(s2, v0)));
  }
}

template<int N, int W, class VT>
DEVINL void g_u2(VT& A, C2 u00, C2 u01, C2 u10, C2 u11) {
  constexpr int M = 1 << (N - 1 - W);
#pragma unroll
  for (int i = 0; i < (1 << N); ++i) if (!(i & M)) {
    const int j = i | M;
    __half2 v0 = vget(A, i), v1 = vget(A, j), v0s = swap2(v0), v1s = swap2(v1);
    vset(A, i, __hfma2(u00.rr, v0, __hfma2(u00.mp, v0s, __hfma2(u01.rr, v1, __hmul2(u01.mp, v1s)))));
    vset(A, j, __hfma2(u10.rr, v0, __hfma2(u10.mp, v0s, __hfma2(u11.rr, v1, __hmul2(u11.mp, v1s)))));
  }
}

template<int N, int C, int T, class VT>
DEVINL void g_cnot(VT& A) {
  constexpr int CM = 1 << (N - 1 - C), TM = 1 << (N - 1 - T);
#pragma unroll
  for (int i = 0; i < (1 << N); ++i) if ((i & CM) && !(i & TM)) {
    const int j = i | TM;
    __half2 t = vget(A, i); vset(A, i, vget(A, j)); vset(A, j, t);
  }
}

template<int N, int K, class VT>
DEVINL void chain_cnot(VT& A) {
  if constexpr (K < N - 1) { g_cnot<N, K, K + 1>(A); chain_cnot<N, K + 1>(A); }
}

// ---------------- per-qubit coefficients (f32) ------------------------------
// forward: u = Rz(phi)Ry(pt)Rx(eta)|0>;  reverse merged: U = Rx(phi)Ry(pt)Rz(eta)

DEVINL void mk_u01(float ce, float se, float cp, float sp, float cf, float sf,
                   c32& u0, c32& u1) {
  u0 = cmulf({cf, -sf}, {cp * ce, sp * se});
  u1 = cmulf({cf,  sf}, {sp * ce, -cp * se});
}

DEVINL void mk_U(float ce, float se, float cp, float sp, float cf, float sf,
                 C2& U00, C2& U01, C2& U10, C2& U11) {
  c32 z = {ce, -se}, zb = {ce, se};
  c32 A = cmulf({cf * cp, -sf * sp}, z);
  c32 T = cmulf({cf * sp,  sf * cp}, zb);
  c32 Cc = cmulf({cf * sp, -sf * cp}, z);
  c32 D = cmulf({cf * cp,  sf * sp}, zb);
  U00 = mkc(A.x, A.y); U01 = mkc(-T.x, -T.y); U10 = mkc(Cc.x, Cc.y); U11 = mkc(D.x, D.y);
}

// per-qubit sincos loader (eta_i<0 -> eta=0)
DEVINL void load_sc(const float* __restrict__ xr, int eta_i, int pt_i, int phi_i,
                    float& ce, float& se, float& cp, float& sp, float& cf, float& sf) {
  float e = (eta_i < 0) ? 0.f : xr[eta_i];
  __sincosf(0.5f * e, &se, &ce);
  __sincosf(0.5f * xr[pt_i], &sp, &cp);
  __sincosf(0.5f * xr[phi_i], &sf, &cf);
}

// product state build by doubling (A[0] must be (1,0) on entry).
// step M's qubit lands at bit (N-1-M). CF(M,u0,u1) supplies the column.
template<int N, int M, class VT, class CF>
DEVINL void build_rec(VT& A, CF cf) {
  if constexpr (M < N) {
    c32 u0, u1; cf(M, u0, u1);
    C2 c0 = mkc(u0.x, u0.y), c1 = mkc(u1.x, u1.y);
#pragma unroll
    for (int j = (1 << M) - 1; j >= 0; --j) {
      __half2 s = vget(A, j);
      vset(A, 2 * j,     cmulc(c0, s));
      vset(A, 2 * j + 1, cmulc(c1, s));
    }
    build_rec<N, M + 1>(A, cf);
  }
}

template<int N, int K, class VT, class CF>
DEVINL void usweep_rec(VT& A, CF cf) {
  if constexpr (K < N) {
    C2 U00, U01, U10, U11;
    cf(K, U00, U01, U10, U11);
    g_u2<N, K>(A, U00, U01, U10, U11);
    usweep_rec<N, K + 1>(A, cf);
  }
}

template<int N, int K, class VT, class CF>
DEVINL void ry_rec(VT& A, CF cf) {
  if constexpr (K < N) {
    __half2 c2, s2, ns2;
    cf(K, c2, s2, ns2);
    g_ry<N, K>(A, c2, s2, ns2);
    ry_rec<N, K + 1>(A, cf);
  }
}

// ---------------- 4-qubit block I (verified math, SSA state) ----------------

template<int I>
DEVINL void sim4h(const float* __restrict__ xr, const float* __restrict__ w, float* z) {
  constexpr int PT[3][4]  = {{5, 4, 35, 34}, {3, 33, 31, 2}, {28, 32, 15, 16}};
  constexpr int ETA[3][4] = {{9, 8, 45, 44}, {7, 43, 41, 6}, {38, 42, 19, 20}};
  constexpr int PHI[3][4] = {{13, 12, 55, 54}, {11, 53, 51, 10}, {48, 52, 23, 24}};
  vreg16 A;
  vset(A, 0, mkamp(1.f, 0.f));
  build_rec<4, 0>(A, [&](int M, c32& u0, c32& u1) {
    float ce, se, cp, sp, cf, sf;
    load_sc(xr, ETA[I][M], PT[I][M], PHI[I][M], ce, se, cp, sp, cf, sf);
    mk_u01(ce, se, cp, sp, cf, sf, u0, u1);
  });
  chain_cnot<4, 0>(A);
  usweep_rec<4, 0>(A, [&](int K, C2& U00, C2& U01, C2& U10, C2& U11) {
    float ce, se, cp, sp, cf, sf;
    load_sc(xr, ETA[I][K], PT[I][K], PHI[I][K], ce, se, cp, sp, cf, sf);
    mk_U(ce, se, cp, sp, cf, sf, U00, U01, U10, U11);
  });

  // t->l CNOT block == flip q0,q1 (mask 12) iff parity(b2,b3) (i&3)
#pragma unroll
  for (int i = 0; i < 16; ++i)
    if (parc(i & 3) && !(i & 8)) {
      __half2 t = vget(A, i); vset(A, i, vget(A, i ^ 12)); vset(A, i ^ 12, t);
    }

  ry_rec<4, 0>(A, [&](int K, __half2& c2, __half2& s2, __half2& ns2) {
    float sv, cv; __sincosf(0.5f * w[K], &sv, &cv);
    c2 = __floats2half2_rn(cv, cv);
    s2 = __floats2half2_rn(sv, sv);
    ns2 = __floats2half2_rn(-sv, -sv);
  });

  // l->t CNOT block == flip q2,q3 (mask 3) iff parity(b0,b1) (i&12)
#pragma unroll
  for (int i = 0; i < 16; ++i)
    if (parc(i & 12) && !(i & 2)) {
      __half2 t = vget(A, i); vset(A, i, vget(A, i ^ 3)); vset(A, i ^ 3, t);
    }

  float cls[4];
#pragma unroll
  for (int c = 0; c < 4; ++c) cls[c] = 0.f;
#pragma unroll
  for (int i = 0; i < 16; ++i) cls[i & 3] = ampsq(vget(A, i), cls[i & 3]);
  float z0 = 0.f, z1 = 0.f;
#pragma unroll
  for (int c = 0; c < 4; ++c) {
    z0 += (c & 2) ? -cls[c] : cls[c];
    z1 += (c & 1) ? -cls[c] : cls[c];
  }
  z[0] = z0; z[1] = z1;
}

// ---------------- role bodies ----------------------------------------------

DEVINL void role4(const float* __restrict__ x,
                  const float* __restrict__ wA, const float* __restrict__ wB,
                  const float* __restrict__ wC,
                  float* __restrict__ out, int B, int s, int rb) {
  const int b = rb * 256 + threadIdx.x;
  if (b >= B) return;
  const float* xr = x + (size_t)b * 56;

  float o[2];
  if (s == 0)      sim4h<0>(xr, wA, o);
  else if (s == 1) sim4h<1>(xr, wB, o);
  else             sim4h<2>(xr, wC, o);

  float* op = out + (size_t)b * 9 + 2 * s;
  op[0] = o[0]; op[1] = o[1];
}

// 7q: qubit 0 = lane parity; local index i = qubits 1..6, qubit k at bit 6-k.
DEVINL void role7(const float* __restrict__ x, const float* __restrict__ wD,
                  float* __restrict__ out, int B, int rb) {
  const int t = rb * 256 + threadIdx.x;
  const int b = t >> 1;
  if (b >= B) return;                 // pairs both-valid or both-invalid
  const bool po = (t & 1) != 0;       // this lane's value of qubit 0

  constexpr int PT[7]  = {0, 14, 30, 26, 29, 27, 17};
  constexpr int ETA[7] = {-1, 18, 40, 36, 39, 37, 21};  // -1 -> zeros (None)
  constexpr int PHI[7] = {1, 22, 50, 46, 49, 47, 25};

  const float* xr = x + (size_t)b * 56;

  vreg64 A;
  vset(A, 0, mkamp(1.f, 0.f));
  // build qubits 1..6 locally: step M = qubit M+1 -> local bit 5-M = 6-(M+1)
  build_rec<6, 0>(A, [&](int M, c32& u0, c32& u1) {
    const int k = M + 1;
    float ce, se, cp, sp, cf, sf;
    load_sc(xr, ETA[k], PT[k], PHI[k], ce, se, cp, sp, cf, sf);
    mk_u01(ce, se, cp, sp, cf, sf, u0, u1);
  });
  { // qubit-0 product factor, selected by lane parity
    float ce, se, cp, sp, cf, sf;
    load_sc(xr, ETA[0], PT[0], PHI[0], ce, se, cp, sp, cf, sf);
    c32 u0, u1; mk_u01(ce, se, cp, sp, cf, sf, u0, u1);
    C2 c0 = mkc(po ? u1.x : u0.x, po ? u1.y : u0.y);
#pragma unroll
    for (int i = 0; i < 64; ++i) vset(A, i, cmulc(c0, vget(A, i)));
  }

  // CNOT(0,1): lanes with q0=1 flip local bit5 (pure per-lane swap)
#pragma unroll
  for (int i = 0; i < 32; ++i) {
    const int j = i | 32;
    __half2 lo = vget(A, i), hi = vget(A, j);
    vset(A, i, po ? hi : lo);
    vset(A, j, po ? lo : hi);
  }
  // CNOT(1,2)..(5,6): local chain; g_cnot<6,C,C+1> = qubits (C+1, C+2)
  chain_cnot<6, 0>(A);

  // merged-U sweep: qubit 0 (cross-lane), then qubits 1..6 (local)
  {
    float ce, se, cp, sp, cf, sf;
    load_sc(xr, ETA[0], PT[0], PHI[0], ce, se, cp, sp, cf, sf);
    C2 U00, U01, U10, U11;
    mk_U(ce, se, cp, sp, cf, sf, U00, U01, U10, U11);
    // out_lane = UA*mine + UB*partner;  UA = po?U11:U00, UB = po?U10:U01
    C2 UA, UB;
    UA.rr = po ? U11.rr : U00.rr; UA.mp = po ? U11.mp : U00.mp;
    UB.rr = po ? U10.rr : U01.rr; UB.mp = po ? U10.mp : U01.mp;
#pragma unroll
    for (int i = 0; i < 64; ++i) {
      __half2 m = vget(A, i), q = lx1(m);
      vset(A, i, __hfma2(UA.rr, m, __hfma2(UA.mp, swap2(m),
                 __hfma2(UB.rr, q, __hmul2(UB.mp, swap2(q))))));
    }
  }
  usweep_rec<6, 0>(A, [&](int W, C2& U00, C2& U01, C2& U10, C2& U11) {
    const int k = W + 1;   // g_u2<6,W> mask 1<<(5-W) == qubit k local bit 6-k
    float ce, se, cp, sp, cf, sf;
    load_sc(xr, ETA[k], PT[k], PHI[k], ce, se, cp, sp, cf, sf);
    mk_U(ce, se, cp, sp, cf, sf, U00, U01, U10, U11);
  });

  // depth loop kept rolled: body stays in L1I
#pragma unroll 1
  for (int d = 0; d < 4; ++d) {
    // P1 (t->l): flip q0..q3 iff parity(q4,q5,q6).  Pairs {i, i^0x38} across
    // lanes: A[i]_po <- old A[i^0x38]_{1-po}
#pragma unroll
    for (int i = 0; i < 64; ++i)
      if (parc(i & 7) && !(i & 0x20)) {
        const int j = i ^ 0x38;
        __half2 t0 = lx1(vget(A, j));
        __half2 t1 = lx1(vget(A, i));
        vset(A, i, t0); vset(A, j, t1);
      }

    // Ry qubit 0 (cross-lane): out = c*mine + (po? s : -s)*partner
    {
      float sv, cv; __sincosf(0.5f * wD[7 * d], &sv, &cv);
      __half2 c2v = __floats2half2_rn(cv, cv);
      __half2 sp2 = __floats2half2_rn(po ? sv : -sv, po ? sv : -sv);
#pragma unroll
      for (int i = 0; i < 64; ++i) {
        __half2 q = lx1(vget(A, i));
        vset(A, i, __hfma2(c2v, vget(A, i), __hmul2(sp2, q)));
      }
    }
    // Ry qubits 1..6 (local)
    ry_rec<6, 0>(A, [&](int W, __half2& c2, __half2& s2, __half2& ns2) {
      float sv, cv; __sincosf(0.5f * wD[7 * d + W + 1], &sv, &cv);
      c2 = __floats2half2_rn(cv, cv);
      s2 = __floats2half2_rn(sv, sv);
      ns2 = __floats2half2_rn(-sv, -sv);
    });

    // P2 (l->t): flip q4..q6 (local ^7) iff parity(q0..q3) = po ^ parc(i&0x38)
#pragma unroll
    for (int i = 0; i < 64; ++i)
      if (!(i & 4)) {            // rep of pair {i, i^7}
        const int j = i ^ 7;
        const bool cond = parc(i & 0x38) ? !po : po;
        __half2 lo = vget(A, i), hi = vget(A, j);
        vset(A, i, cond ? hi : lo);
        vset(A, j, cond ? lo : hi);
      }
  }

  // readout: class c = q4q5q6 = i&7 (local); pair-sum cross-lane
  float cls[8];
#pragma unroll
  for (int c = 0; c < 8; ++c) cls[c] = 0.f;
#pragma unroll
  for (int i = 0; i < 64; ++i) cls[i & 7] = ampsq(vget(A, i), cls[i & 7]);
  float z4 = 0.f, z5 = 0.f, z6 = 0.f;
#pragma unroll
  for (int c = 0; c < 8; ++c) {
    z4 += (c & 4) ? -cls[c] : cls[c];
    z5 += (c & 2) ? -cls[c] : cls[c];
    z6 += (c & 1) ? -cls[c] : cls[c];
  }
  z4 += lx1f(z4); z5 += lx1f(z5); z6 += lx1f(z6);
  if (!po) {
    float* op = out + (size_t)b * 9 + 6;
    op[0] = z4; op[1] = z5; op[2] = z6;
  }
}

// ---------------- single fused-dispatch kernel ------------------------------

__global__ void
__attribute__((amdgpu_flat_work_group_size(256, 256), amdgpu_waves_per_eu(2, 4)))
k_all(const float* __restrict__ x,
      const float* __restrict__ wA, const float* __restrict__ wB,
      const float* __restrict__ wC, const float* __restrict__ wD,
      float* __restrict__ out, int B, int gx) {
  const int bx = blockIdx.x;
  if (bx < 3 * gx) {
    const int s = (bx >= 2 * gx) ? 2 : (int)(bx >= gx);  // block-uniform
    role4(x, wA, wB, wC, out, B, s, bx - s * gx);
  } else {
    role7(x, wD, out, B, bx - 3 * gx);
  }
}

// ---------------- launch ----------------------------------------------------

extern "C" void kernel_launch(void* const* d_in, const int* in_sizes, int n_in,
                              void* d_out, int out_size, void* d_ws, size_t ws_size,
                              hipStream_t stream) {
  const float* x  = (const float*)d_in[0];
  const float* wA = (const float*)d_in[1];
  const float* wB = (const float*)d_in[2];
  const float* wC = (const float*)d_in[3];
  const float* wD = (const float*)d_in[4];
  float* out = (float*)d_out;
  const int B = in_sizes[0] / 56;
  const int threads = 256;

  const int gx = (B + threads - 1) / threads;          // blocks per 4q role
  const int gy = (2 * B + threads - 1) / threads;      // blocks for 7q role
  k_all<<<3 * gx + gy, threads, 0, stream>>>(x, wA, wB, wC, wD, out, B, gx);
}